// Round 12
// baseline (298.217 us; speedup 1.0000x reference)
//
#include <hip/hip_runtime.h>
#include <hip/hip_bf16.h>

typedef __attribute__((ext_vector_type(4))) float f32x4;
typedef __attribute__((ext_vector_type(16))) float f32x16;
typedef __attribute__((ext_vector_type(8))) short short8;
typedef unsigned short ushort_t;

#define BATCH 256
#define PDIM 512
#define MDIM 768
#define XCOLS 1280
#define PROJ 512
#define HID 256
#define KTOT (PDIM * MDIM)

#define BN 32
#define NT 16       // N tiles (512/32)
#define PSPLIT 32   // pi splits
#define PI_PER 16   // 512/32
#define NJW 12      // j windows of 64
#define NSTEPS 192  // pil = s&15 (inner), jw = s>>4

__device__ __forceinline__ ushort_t f2bf(float f) {
  __hip_bfloat16 h = __float2bfloat16(f);
  return __builtin_bit_cast(ushort_t, h);
}
__device__ __forceinline__ float bf2f(ushort_t u) {
  union { unsigned int i; float f; } c;
  c.i = ((unsigned int)u) << 16;
  return c.f;
}

// ---------------- prep: fragment-ordered bf16(m) ----------------
// mF chunk c = ((jw*8 + mf)*4 + ks)*64 + lane ; element e of chunk:
//   bf16( m[row = mf*32+(lane&31)][k = jw*64 + ks*16 + (lane>>5)*8 + e] )
__global__ void prep_kernel(const float* __restrict__ x, ushort_t* __restrict__ mF) {
  int tid = blockIdx.x * blockDim.x + threadIdx.x;
  int nth = gridDim.x * blockDim.x;
  for (int c = tid; c < NJW * 8 * 4 * 64; c += nth) {
    int lane = c & 63;
    int ks = (c >> 6) & 3;
    int mf = (c >> 8) & 7;
    int jw = c >> 11;
    int row = mf * 32 + (lane & 31);
    int k0 = jw * 64 + ks * 16 + ((lane >> 5) << 3);
    const float* src = x + row * XCOLS + PDIM + k0;
    f32x4 v0 = *(const f32x4*)src;
    f32x4 v1 = *(const f32x4*)(src + 4);
    short8 o;
#pragma unroll
    for (int i = 0; i < 4; ++i) {
      o[i] = (short)f2bf(v0[i]);
      o[i + 4] = (short)f2bf(v1[i]);
    }
    ((short8*)mF)[c] = o;
  }
}

// ---------------- main einsum GEMM ----------------
// r9 skeleton; W1 staging via __builtin_amdgcn_global_load_lds (DMA to LDS,
// no VGPR round-trip, no stage-side cvt). Triple-buffered f32 tiles, prefetch
// distance 2, counted vmcnt(1) per step (never full drain in-loop). LDS layout
// linear for the DMA; read-side XOR swizzle realized by PRE-SWIZZLING the
// per-lane global source (rule 21 / m201 pattern). cvt f32->bf16 at consumer.
__global__ __launch_bounds__(512, 4)
void einsum_kernel(const float* __restrict__ W1, const ushort_t* __restrict__ mF,
                   const float* __restrict__ x, float* __restrict__ outp,
                   int atomic_mode) {
  __shared__ __align__(16) char Bs[3][8192];  // 3 x 8 KB f32 tiles [32 n][64 k]
  __shared__ float pl[PI_PER * BATCH];        // 16 KB p[pil][b]

  const int ntile = blockIdx.x & 15;
  const int ps    = blockIdx.x >> 4;
  const int pi0   = ps * PI_PER;
  const int n0    = ntile * BN;
  const int t     = threadIdx.x;
  const int lane  = t & 63;
  const int w     = t >> 6;   // 8 waves; wave w owns batch rows 32w..32w+31
  const int hi    = lane >> 5;

  // stage p: thread t -> batch row t&255, pi half t>>8 (8 floats)
  {
    const int b = t & 255, half = t >> 8;
    const float* xr = x + (size_t)b * XCOLS + pi0 + half * 8;
    f32x4 v0 = *(const f32x4*)xr;
    f32x4 v1 = *(const f32x4*)(xr + 4);
#pragma unroll
    for (int i = 0; i < 4; ++i) {
      pl[(half * 8 + i) * BATCH + b]     = v0[i];
      pl[(half * 8 + 4 + i) * BATCH + b] = v1[i];
    }
  }

  // DMA write mapping: wave w fills bytes w*1024..+1023 (rows 4w..4w+3).
  // physical chunk (r, q) holds logical bytes q ^ ((r&15)<<4)  -> pre-swizzled src
  const int wr = 4 * w + (lane >> 4);
  const int wo = ((lane & 15) << 4) ^ ((wr & 15) << 4);
  const char* wsrc = (const char*)(W1 + (size_t)(n0 + wr) * KTOT + (size_t)pi0 * MDIM) + wo;

  // read mapping: row r=lane&31, logical byte kb -> physical r*256 + (kb ^ ((r&15)<<4))
  const int r256 = (lane & 31) << 8;
  const int sz_  = (lane & 15) << 4;
  const int hi32 = hi << 5;

  // A fragment chunks in regs: chunk = jw*2048 + w*256 + ks*64 + lane
  const short8* mv = (const short8*)mF;
  const int mbase = w * 256 + lane;
  short8 ac0 = mv[mbase];
  short8 ac1 = mv[mbase + 64];
  short8 ac2 = mv[mbase + 128];
  short8 ac3 = mv[mbase + 192];

#define KOFFB(s) (((((s) & 15) * MDIM) + (((s) >> 4) * 64)) * 4)  // byte offset

  // prologue: DMA tiles 0,1
  __builtin_amdgcn_global_load_lds((const unsigned int*)(wsrc + KOFFB(0)),
                                   (unsigned int*)(&Bs[0][0] + (w << 10)), 16, 0, 0);
  __builtin_amdgcn_global_load_lds((const unsigned int*)(wsrc + KOFFB(1)),
                                   (unsigned int*)(&Bs[1][0] + (w << 10)), 16, 0, 0);

  f32x16 fa;
#pragma unroll
  for (int i = 0; i < 16; ++i) fa[i] = 0.f;

  __syncthreads();  // drains prologue DMA + pl writes (one-time full drain)

  for (int s = 0; s < NSTEPS; ++s) {
    // issue(s) forced complete; issue(s+1) stays in flight (counted, never 0)
    asm volatile("s_waitcnt vmcnt(1)" ::: "memory");
    asm volatile("s_waitcnt lgkmcnt(0)" ::: "memory");
    __builtin_amdgcn_sched_barrier(0);
    __builtin_amdgcn_s_barrier();
    asm volatile("" ::: "memory");

    // issue(s+2): its buffer's readers drained at the barrier above (wrap at tail)
    {
      int s2 = s + 2; if (s2 >= NSTEPS) s2 -= NSTEPS;
      const int b2 = s2 % 3;
      __builtin_amdgcn_global_load_lds((const unsigned int*)(wsrc + KOFFB(s2)),
                                       (unsigned int*)(&Bs[b2][0] + (w << 10)), 16, 0, 0);
    }

    const char* bsp = &Bs[s % 3][0];
    const float pa = pl[(s & 15) * BATCH + (w << 5) + (lane & 31)];

#define GENMM(AC, KS)                                                      \
    {                                                                      \
      const int kb = (KS) * 64 + hi32;                                     \
      f32x4 b0 = *(const f32x4*)(bsp + r256 + ((kb) ^ sz_));               \
      f32x4 b1 = *(const f32x4*)(bsp + r256 + ((kb + 16) ^ sz_));          \
      short8 bvh, aA;                                                      \
      _Pragma("unroll")                                                    \
      for (int i2 = 0; i2 < 4; ++i2) {                                     \
        bvh[i2]     = (short)f2bf(b0[i2]);                                 \
        bvh[4 + i2] = (short)f2bf(b1[i2]);                                 \
      }                                                                    \
      _Pragma("unroll")                                                    \
      for (int e = 0; e < 8; ++e)                                          \
        aA[e] = (short)f2bf(pa * bf2f((ushort_t)AC[e]));                   \
      fa = __builtin_amdgcn_mfma_f32_32x32x16_bf16(aA, bvh, fa, 0, 0, 0);  \
    }
    GENMM(ac0, 0)
    GENMM(ac1, 1)
    GENMM(ac2, 2)
    GENMM(ac3, 3)
#undef GENMM

    // jw boundary: reload A frags for next jw (compiler-managed counted waits)
    if ((s & 15) == 15) {
      int jn = (s >> 4) + 1; if (jn >= NJW) jn = 0;
      const short8* srcn = mv + jn * 2048 + mbase;
      ac0 = srcn[0];
      ac1 = srcn[64];
      ac2 = srcn[128];
      ac3 = srcn[192];
    }
  }
#undef KOFFB
  asm volatile("s_waitcnt vmcnt(0)" ::: "memory");  // drain wrapped tail DMAs

  // ---- C write: row = 32w + (rr&3)+8*(rr>>2)+4*hi, col = n0+(lane&31) ----
  const int col = n0 + (lane & 31);
  const int rb2 = w * 32 + (hi << 2);
  if (atomic_mode) {
#pragma unroll
    for (int rr = 0; rr < 16; ++rr) {
      int row = rb2 + (rr & 3) + ((rr >> 2) << 3);
      atomicAdd(&outp[(size_t)row * PROJ + col], fa[rr]);
    }
  } else {
    float* dst = outp + (size_t)ps * BATCH * PROJ;
#pragma unroll
    for (int rr = 0; rr < 16; ++rr) {
      int row = rb2 + (rr & 3) + ((rr >> 2) << 3);
      dst[(size_t)row * PROJ + col] = fa[rr];
    }
  }
}

// ---------------- reduce + LN + MLP ----------------
__global__ __launch_bounds__(256)
void mlp_kernel(const float* __restrict__ part, int nps,
                const float* __restrict__ b1, const float* __restrict__ lng,
                const float* __restrict__ lnb, const float* __restrict__ W2,
                const float* __restrict__ b2, const float* __restrict__ g1,
                const float* __restrict__ bb1, const float* __restrict__ W3,
                const float* __restrict__ b3, const float* __restrict__ g2,
                const float* __restrict__ bb2, const float* __restrict__ W4,
                const float* __restrict__ b4, float* __restrict__ out) {
  __shared__ float h1[PROJ];
  __shared__ float h2[HID];
  __shared__ float h3[HID / 2];
  __shared__ float red[16];
  const int b = blockIdx.x, t = threadIdx.x;

  float f0 = 0.f, f1 = 0.f;
  const float* p0 = part + (size_t)b * PROJ + t;
#pragma unroll 4
  for (int s = 0; s < nps; ++s) {
    f0 += p0[0];
    f1 += p0[256];
    p0 += (size_t)BATCH * PROJ;
  }
  f0 += b1[t];
  f1 += b1[t + 256];

  float sum = f0 + f1, ss = f0 * f0 + f1 * f1;
#pragma unroll
  for (int o = 32; o > 0; o >>= 1) {
    sum += __shfl_xor(sum, o);
    ss  += __shfl_xor(ss, o);
  }
  const int wv = t >> 6, ln = t & 63;
  if (ln == 0) { red[wv] = sum; red[8 + wv] = ss; }
  __syncthreads();
  sum = red[0] + red[1] + red[2] + red[3];
  ss  = red[8] + red[9] + red[10] + red[11];
  float mu   = sum * (1.f / 512.f);
  float var  = ss * (1.f / 512.f) - mu * mu;
  float rstd = rsqrtf(var + 1e-5f);
  h1[t]       = fmaxf(0.f, (f0 - mu) * rstd * lng[t] + lnb[t]);
  h1[t + 256] = fmaxf(0.f, (f1 - mu) * rstd * lng[t + 256] + lnb[t + 256]);
  __syncthreads();

  const float bninv = rsqrtf(1.f + 1e-5f);
  {
    const f32x4* wr = (const f32x4*)(W2 + (size_t)t * PROJ);
    const f32x4* hv = (const f32x4*)h1;
    float a = 0.f;
#pragma unroll 4
    for (int i = 0; i < PROJ / 4; ++i) {
      f32x4 wq = wr[i], h = hv[i];
      a += wq[0] * h[0] + wq[1] * h[1] + wq[2] * h[2] + wq[3] * h[3];
    }
    h2[t] = fmaxf(0.f, (a + b2[t]) * bninv * g1[t] + bb1[t]);
  }
  __syncthreads();
  if (t < 128) {
    const f32x4* wr = (const f32x4*)(W3 + (size_t)t * HID);
    const f32x4* hv = (const f32x4*)h2;
    float a = 0.f;
#pragma unroll 4
    for (int i = 0; i < HID / 4; ++i) {
      f32x4 wq = wr[i], h = hv[i];
      a += wq[0] * h[0] + wq[1] * h[1] + wq[2] * h[2] + wq[3] * h[3];
    }
    h3[t] = fmaxf(0.f, (a + b3[t]) * bninv * g2[t] + bb2[t]);
  }
  __syncthreads();
  if (t < 2) {
    const float* wr = W4 + t * 128;
    float a = 0.f;
#pragma unroll 4
    for (int i = 0; i < 128; ++i) a += wr[i] * h3[i];
    out[b * 2 + t] = a + b4[t];
  }
}

extern "C" void kernel_launch(void* const* d_in, const int* in_sizes, int n_in,
                              void* d_out, int out_size, void* d_ws, size_t ws_size,
                              hipStream_t stream) {
  const float* x   = (const float*)d_in[0];
  const float* W1  = (const float*)d_in[1];
  const float* b1  = (const float*)d_in[2];
  const float* lng = (const float*)d_in[3];
  const float* lnb = (const float*)d_in[4];
  const float* W2  = (const float*)d_in[5];
  const float* b2  = (const float*)d_in[6];
  const float* g1  = (const float*)d_in[7];
  const float* bb1 = (const float*)d_in[8];
  const float* W3  = (const float*)d_in[9];
  const float* b3  = (const float*)d_in[10];
  const float* g2  = (const float*)d_in[11];
  const float* bb2 = (const float*)d_in[12];
  const float* W4  = (const float*)d_in[13];
  const float* b4  = (const float*)d_in[14];
  float* out = (float*)d_out;

  char* ws = (char*)d_ws;
  ushort_t* mF = (ushort_t*)ws;              // 384 KB (fragment-ordered bf16 m)
  float* big   = (float*)(ws + 524288);      // split-K partials

  size_t need = 524288 + (size_t)PSPLIT * BATCH * PROJ * 4;  // ~17.3 MB
  bool partial = ws_size >= need;

  hipLaunchKernelGGL(prep_kernel, dim3(256), dim3(256), 0, stream, x, mF);
  if (partial) {
    hipLaunchKernelGGL(einsum_kernel, dim3(NT * PSPLIT), dim3(512), 0, stream,
                       W1, mF, x, big, 0);
    hipLaunchKernelGGL(mlp_kernel, dim3(BATCH), dim3(256), 0, stream, big, PSPLIT,
                       b1, lng, lnb, W2, b2, g1, bb1, W3, b3, g2, bb2, W4, b4, out);
  } else {
    hipMemsetAsync(big, 0, (size_t)BATCH * PROJ * 4, stream);
    hipLaunchKernelGGL(einsum_kernel, dim3(NT * PSPLIT), dim3(512), 0, stream,
                       W1, mF, x, big, 1);
    hipLaunchKernelGGL(mlp_kernel, dim3(BATCH), dim3(256), 0, stream, big, 1,
                       b1, lng, lnb, W2, b2, g1, bb1, W3, b3, g2, bb2, W4, b4, out);
  }
}